// Round 3
// baseline (459.538 us; speedup 1.0000x reference)
//
#include <hip/hip_runtime.h>
#include <math.h>

// ---------------- constants from the reference ----------------
#define NCLS 10
#define TOPK 1000
#define DETS 100
#define CANDMAX 4096
#define SLOTS 16   // 16 * 64 lanes = 1024 >= TOPK

// score histogram: scores > 0.05 have (bits>>16) in [0x3D4C, 0x3F80) -> 564 bins
#define BIN0 0x3D4Cu
#define NBINS 576
#define NBLK 64    // blocks per image for the score/compact passes

__device__ __forceinline__ float sigmoidf_(float x) {
    return 1.0f / (1.0f + expf(-x));
}

// K1: fused score + per-block LDS histogram (+ optional score cache).
// score = sigmoid(max(logits)) == max(sigmoid(logits)) (sigmoid monotone).
__global__ __launch_bounds__(256) void k_score_hist(const float* __restrict__ logits,
                                                    float* __restrict__ scores,
                                                    unsigned* __restrict__ hist,
                                                    int A, int use_scores) {
    __shared__ unsigned h[NBINS];
    int img = blockIdx.y;
    for (int i = threadIdx.x; i < NBINS; i += 256) h[i] = 0;
    __syncthreads();

    const float* base = logits + (size_t)img * A * NCLS;
    int nquad = A >> 2;   // 4 anchors (= 40 floats = 10 float4) per iteration
    for (int q = blockIdx.x * 256 + threadIdx.x; q < nquad; q += NBLK * 256) {
        const float4* lp = (const float4*)(base + (size_t)q * 40);
        float f[40];
#pragma unroll
        for (int i = 0; i < 10; ++i) ((float4*)f)[i] = lp[i];
        float4 s4;
        float* sv = &s4.x;
#pragma unroll
        for (int j = 0; j < 4; ++j) {
            float m = f[10 * j];
#pragma unroll
            for (int c = 1; c < 10; ++c) m = fmaxf(m, f[10 * j + c]);
            float sc = sigmoidf_(m);
            sc = (sc > 0.05f) ? sc : 0.0f;
            sv[j] = sc;
            if (sc > 0.0f) {
                unsigned bin = (__float_as_uint(sc) >> 16) - BIN0;
                if (bin >= NBINS) bin = NBINS - 1;   // defensive clamp
                atomicAdd(&h[bin], 1u);
            }
        }
        if (use_scores) ((float4*)(scores + (size_t)img * A))[q] = s4;
    }
    // scalar tail (A % 4), handled by block x==0 of each image
    int tail0 = nquad << 2;
    if (blockIdx.x == 0) {
        for (int a = tail0 + (int)threadIdx.x; a < A; a += 256) {
            const float* lp2 = base + (size_t)a * NCLS;
            float m = lp2[0];
            for (int c = 1; c < 10; ++c) m = fmaxf(m, lp2[c]);
            float sc = sigmoidf_(m);
            sc = (sc > 0.05f) ? sc : 0.0f;
            if (use_scores) scores[(size_t)img * A + a] = sc;
            if (sc > 0.0f) {
                unsigned bin = (__float_as_uint(sc) >> 16) - BIN0;
                if (bin >= NBINS) bin = NBINS - 1;
                atomicAdd(&h[bin], 1u);
            }
        }
    }
    __syncthreads();
    for (int i = threadIdx.x; i < NBINS; i += 256) {
        unsigned c = h[i];
        if (c) atomicAdd(&hist[(size_t)img * NBINS + i], c);
    }
}

// K2: per image, single wave: smallest global bin P with suffix count >= TOPK.
__global__ void k_findP(const unsigned* __restrict__ hist, unsigned* __restrict__ P) {
    int img = blockIdx.x;
    int lane = threadIdx.x;               // 64 threads
    const unsigned* h = hist + (size_t)img * NBINS;
    unsigned b[9];
    unsigned s = 0;
#pragma unroll
    for (int j = 0; j < 9; ++j) { b[j] = h[lane * 9 + j]; s += b[j]; }
    unsigned suf = s;                     // inclusive suffix scan across lanes
#pragma unroll
    for (int d = 1; d < 64; d <<= 1) {
        unsigned o = __shfl_down(suf, d);
        if (lane + d < 64) suf += o;
    }
    unsigned above = __shfl_down(suf, 1);
    if (lane == 63) above = 0;
    if (lane == 0 && suf < (unsigned)TOPK) P[img] = 0u;  // pathological fallback
    if (above < (unsigned)TOPK && suf >= (unsigned)TOPK) {
        unsigned cum = above;
        for (int j = 8; j >= 0; --j) {
            cum += b[j];
            if (cum >= (unsigned)TOPK) { P[img] = BIN0 + (unsigned)(lane * 9 + j); break; }
        }
    }
}

// K3: compact candidates (top16 >= P) with wave-aggregated counter atomics.
__global__ __launch_bounds__(256) void k_compact(const float* __restrict__ logits,
                                                 const float* __restrict__ scores,
                                                 const unsigned* __restrict__ P,
                                                 unsigned* __restrict__ ctr,
                                                 unsigned long long* __restrict__ cand,
                                                 int A) {
    int img = blockIdx.y;
    unsigned p = P[img];
    int lane = threadIdx.x & 63;
    int nquad = A >> 2;
    for (int q = blockIdx.x * 256 + threadIdx.x; q < nquad; q += NBLK * 256) {
        float sv[4];
        if (scores) {
            float4 t = ((const float4*)(scores + (size_t)img * A))[q];
            sv[0] = t.x; sv[1] = t.y; sv[2] = t.z; sv[3] = t.w;
        } else {
            const float* lp = logits + ((size_t)img * A + (size_t)q * 4) * NCLS;
            float f[40];
#pragma unroll
            for (int i = 0; i < 10; ++i) ((float4*)f)[i] = ((const float4*)lp)[i];
#pragma unroll
            for (int j = 0; j < 4; ++j) {
                float m = f[10 * j];
#pragma unroll
                for (int c = 1; c < 10; ++c) m = fmaxf(m, f[10 * j + c]);
                float sc = sigmoidf_(m);
                sv[j] = (sc > 0.05f) ? sc : 0.0f;
            }
        }
#pragma unroll
        for (int j = 0; j < 4; ++j) {
            unsigned bits = __float_as_uint(sv[j]);
            bool take = (bits >> 16) >= p;
            unsigned long long mask = __ballot(take);
            if (mask) {
                int cnt = __popcll(mask);
                int leader = __ffsll((unsigned long long)mask) - 1;
                unsigned pos = 0;
                if (lane == leader) pos = atomicAdd(&ctr[img], (unsigned)cnt);
                pos = (unsigned)__shfl((int)pos, leader);
                if (take) {
                    unsigned slot = pos + (unsigned)__popcll(mask & ((1ull << lane) - 1ull));
                    if (slot < CANDMAX) {
                        unsigned a = (unsigned)(q * 4 + j);
                        cand[(size_t)img * CANDMAX + slot] =
                            ((unsigned long long)bits << 32) | (unsigned)(~a);
                    }
                }
            }
        }
    }
    // scalar tail
    int tail0 = nquad << 2;
    if (blockIdx.x == 0) {
        for (int a = tail0 + (int)threadIdx.x; a < A; a += 256) {
            float sc;
            if (scores) sc = scores[(size_t)img * A + a];
            else {
                const float* lp = logits + ((size_t)img * A + a) * NCLS;
                float m = lp[0];
                for (int c = 1; c < 10; ++c) m = fmaxf(m, lp[c]);
                float s = sigmoidf_(m);
                sc = (s > 0.05f) ? s : 0.0f;
            }
            unsigned bits = __float_as_uint(sc);
            if ((bits >> 16) >= p) {
                unsigned pos = atomicAdd(&ctr[img], 1u);
                if (pos < CANDMAX)
                    cand[(size_t)img * CANDMAX + pos] =
                        ((unsigned long long)bits << 32) | (unsigned)(~a);
            }
        }
    }
}

// K4: per image bitonic sort; adaptive length (n is typically ~1000-1400).
__global__ __launch_bounds__(1024) void k_sort(const unsigned long long* __restrict__ cand,
                                               const unsigned* __restrict__ ctr,
                                               unsigned* __restrict__ top_idx,
                                               float* __restrict__ top_sc, int A) {
    __shared__ unsigned long long key[CANDMAX];
    int img = blockIdx.x;
    unsigned n = ctr[img];
    if (n > CANDMAX) n = CANDMAX;
    int L = (n <= 1024) ? 1024 : (n <= 2048) ? 2048 : CANDMAX;
    for (int i = threadIdx.x; i < L; i += 1024)
        key[i] = (i < (int)n) ? ~cand[(size_t)img * CANDMAX + i] : ~0ull;
    __syncthreads();
    for (int k = 2; k <= L; k <<= 1) {
        for (int j = k >> 1; j > 0; j >>= 1) {
            for (int i = threadIdx.x; i < L; i += 1024) {
                int l = i ^ j;
                if (l > i) {
                    unsigned long long va = key[i], vb = key[l];
                    bool up = ((i & k) == 0);
                    if (up ? (va > vb) : (va < vb)) { key[i] = vb; key[l] = va; }
                }
            }
            __syncthreads();
        }
    }
    for (int t = threadIdx.x; t < TOPK; t += 1024) {
        unsigned long long ik = key[t];           // ik = ~orig
        unsigned idx = (unsigned)ik;              // low 32 of ~orig == original index
        if (idx >= (unsigned)A) idx = 0;          // fault insurance (pathological only)
        top_idx[img * TOPK + t] = idx;
        top_sc[img * TOPK + t] = __uint_as_float(~(unsigned)(ik >> 32));
    }
}

// K5: soft-NMS (frontier fast path) + register-resident incremental greedy NMS.
// All loop-carried state lives in registers: picked boxes for the greedy check
// are stored at lane (t&63), reg slot (t>>6) (uniform -> static indexing);
// frontier tracking uses a wave-uniform slow-pick list (no shuffles in the
// common path). LDS pick arrays are write-only inside the loop (emit reads
// them after), so no LDS read-after-write dependency remains per pick.
__global__ __launch_bounds__(256, 1) void k_nms(const float* __restrict__ logits,
                                                const float* __restrict__ rel,
                                                const float* __restrict__ anch,
                                                const unsigned* __restrict__ top_idx,
                                                const float* __restrict__ top_sc,
                                                float* __restrict__ out, int A, int B) {
    __shared__ float s_box[TOPK][4];
    __shared__ int   s_lab[TOPK];
    __shared__ float s_pbox[TOPK][4];
    __shared__ int   s_plab[TOPK];
    __shared__ float s_psc[TOPK];
    __shared__ int   s_alive[TOPK];

    const float CLIPV = 4.135166556742356f;  // log(1000/16)
    const float EPS = 1e-7f;
    const float W_ = 1333.0f, H_ = 800.0f;

    int img = blockIdx.x;
    int tid = threadIdx.x;

    // ---- Phase A (all 256 threads): decode candidates into LDS ----
    for (int t = tid; t < TOPK; t += 256) {
        unsigned ai = top_idx[img * TOPK + t];
        const float* lp = logits + ((size_t)img * A + ai) * NCLS;
        float best = sigmoidf_(lp[0]); int lbb = 0;
#pragma unroll
        for (int cc = 1; cc < NCLS; ++cc) {
            float v = sigmoidf_(lp[cc]);
            if (v > best) { best = v; lbb = cc; }
        }
        const float* rp = rel + ((size_t)img * A + ai) * 4;
        const float* ap = anch + (size_t)ai * 4;
        float a0 = ap[0], a1 = ap[1], a2 = ap[2], a3 = ap[3];
        float wa = a2 - a0, ha = a3 - a1;
        float cxa = a0 + 0.5f * wa, cya = a1 + 0.5f * ha;
        float dx = rp[0], dy = rp[1];
        float dw = fminf(rp[2], CLIPV), dh = fminf(rp[3], CLIPV);
        float cx = dx * wa + cxa, cy = dy * ha + cya;
        float w = expf(dw) * wa, h = expf(dh) * ha;
        s_box[t][0] = fminf(fmaxf(cx - 0.5f * w, 0.0f), W_);
        s_box[t][1] = fminf(fmaxf(cy - 0.5f * h, 0.0f), H_);
        s_box[t][2] = fminf(fmaxf(cx + 0.5f * w, 0.0f), W_);
        s_box[t][3] = fminf(fmaxf(cy + 0.5f * h, 0.0f), H_);
        s_lab[t] = lbb;
    }
    __syncthreads();
    if (tid >= 64) return;          // wave 0 only from here; no more barriers
    int lane = tid;

    // ---- load 16 slots/lane into registers (static indices only) ----
    float sc[SLOTS], x1[SLOTS], y1[SLOTS], x2[SLOTS], y2[SLOTS], ar[SLOTS];
    int lb[SLOTS];
#pragma unroll
    for (int j = 0; j < SLOTS; ++j) {
        int c = lane + (j << 6);
        if (c < TOPK) {
            float4 bb = *(const float4*)&s_box[c][0];
            x1[j] = bb.x; y1[j] = bb.y; x2[j] = bb.z; y2[j] = bb.w;
            ar[j] = (bb.z - bb.x) * (bb.w - bb.y);
            lb[j] = s_lab[c];
            sc[j] = top_sc[img * TOPK + c];
        } else {
            sc[j] = -2.0f; lb[j] = -1;
            x1[j] = y1[j] = x2[j] = y2[j] = ar[j] = 0.0f;
        }
    }

    // register pick store: pick p lives at lane (p&63), slot (p>>6), p < 512
    float gx[8], gy[8], gz[8], gw[8];
    unsigned amask = 0;     // alive bits of my stored picks
#pragma unroll
    for (int k = 0; k < 8; ++k) { gx[k] = 0.0f; gy[k] = 0.0f; gz[k] = 0.0f; gw[k] = 0.0f; }

    // aw fallback bitmask: lane l (<16) owns candidate indices [64l, 64l+64)
    unsigned long long aw = 0;
    if (lane < 15) aw = ~0ull;
    else if (lane == 15) aw = (1ull << (TOPK - 15 * 64)) - 1;   // 40 bits

    // wave-uniform slow-pick list (picks that were not the frontier)
    int slow[8];
#pragma unroll
    for (int i = 0; i < 8; ++i) slow[i] = -1;
    int nslow = 0;
    bool slow_ovf = false;

    int f = 0;            // frontier: lowest unpicked index
    int nconf = 0;        // confirmed greedy-alive detections
    int M = TOPK;

    // prefetch for t=0 (f=0)
    float4 fb = *(const float4*)&s_box[0][0];
    int flab = s_lab[0];
    float cf = __shfl(sc[0], 0);

    for (int t = 0; t < TOPK; ++t) {
        // per-lane max over slots (max3-friendly grouping)
        float lm = fmaxf(fmaxf(fmaxf(sc[0], sc[1]), sc[2]),
                         fmaxf(fmaxf(sc[3], sc[4]), sc[5]));
        float lm2 = fmaxf(fmaxf(fmaxf(sc[6], sc[7]), sc[8]),
                          fmaxf(fmaxf(sc[9], sc[10]), sc[11]));
        float lm3 = fmaxf(fmaxf(sc[12], sc[13]), fmaxf(sc[14], sc[15]));
        lm = fmaxf(lm, fmaxf(lm2, lm3));

        int pick; float pcur; float4 pb; int plab_;
        unsigned long long bb = __ballot(lm > cf);
        if (bb == 0) {
            // common path: frontier is the global argmax (ties -> lowest index = f)
            pick = f; pcur = cf; pb = fb; plab_ = flab;
        } else {
            // rare path: full argmax reduce (value desc, index asc)
            float bv = sc[0]; int bi = lane;
#pragma unroll
            for (int j = 1; j < SLOTS; ++j) {
                int e = lane + (j << 6);
                if (sc[j] > bv) { bv = sc[j]; bi = e; }
            }
#pragma unroll
            for (int d = 32; d; d >>= 1) {
                float ov = __shfl_xor(bv, d);
                int oi = __shfl_xor(bi, d);
                if (ov > bv || (ov == bv && oi < bi)) { bv = ov; bi = oi; }
            }
            pick = bi; pcur = bv;
            pb = *(const float4*)&s_box[pick][0];
            plab_ = s_lab[pick];
        }

        float psc = fmaxf(pcur, 0.0f);

        // ---- greedy survival of pick t vs earlier ALIVE picks (registers) ----
        bool alive = (psc > 0.3f);
        if (alive && t > 0) {
            float pa = (pb.z - pb.x) * (pb.w - pb.y);
            bool sup = false;
#pragma unroll
            for (int k = 0; k < 8; ++k) {
                if ((k << 6) < t) {                 // uniform guard
                    int p = lane + (k << 6);
                    if (p < t && ((amask >> k) & 1u)) {
                        float qx = gx[k], qy = gy[k], qz = gz[k], qw = gw[k];
                        float lx = fmaxf(pb.x, qx), ly = fmaxf(pb.y, qy);
                        float rx = fminf(pb.z, qz), ry = fminf(pb.w, qw);
                        float iw = fmaxf(rx - lx, 0.0f), ih = fmaxf(ry - ly, 0.0f);
                        float inter = iw * ih;
                        float qa = (qz - qx) * (qw - qy);
                        float iou = inter / (pa + qa - inter + EPS);
                        sup = sup || (iou > 0.8f);
                    }
                }
            }
            if (t > 512) {   // cold fallback: picks >= 512 live only in LDS
                for (int k = 8; (k << 6) < t; ++k) {
                    int p = lane + (k << 6);
                    int pc = (p < t) ? p : 0;
                    float4 qb = *(const float4*)&s_pbox[pc][0];
                    int ga = s_alive[pc];
                    if (p < t && ga) {
                        float lx = fmaxf(pb.x, qb.x), ly = fmaxf(pb.y, qb.y);
                        float rx = fminf(pb.z, qb.z), ry = fminf(pb.w, qb.w);
                        float iw = fmaxf(rx - lx, 0.0f), ih = fmaxf(ry - ly, 0.0f);
                        float inter = iw * ih;
                        float qa = (qb.z - qb.x) * (qb.w - qb.y);
                        float iou = inter / (pa + qa - inter + EPS);
                        sup = sup || (iou > 0.8f);
                    }
                }
            }
            alive = (__ballot(sup) == 0ull);
        }

        // capture pick t into registers (owner lane) and LDS (posted, for emit)
        {
            bool cap = (lane == (t & 63));
            int k0 = t >> 6;                        // uniform
#pragma unroll
            for (int k = 0; k < 8; ++k) {
                if (k == k0 && cap) {
                    gx[k] = pb.x; gy[k] = pb.y; gz[k] = pb.z; gw[k] = pb.w;
                    if (alive) amask |= (1u << k);
                }
            }
        }
        if (lane == 0) {
            *(float4*)&s_pbox[t][0] = pb;
            s_plab[t] = plab_;
            s_psc[t] = psc;
            s_alive[t] = alive ? 1 : 0;
        }

        nconf += alive ? 1 : 0;
        if (nconf >= DETS) { M = t + 1; break; }   // exit BEFORE dead decay work

        // ---- decay all slots (branch-free; expf(-0)=1.0 exact for non-match) ----
        float wax = (pb.z - pb.x) * (pb.w - pb.y);
#pragma unroll
        for (int j = 0; j < SLOTS; ++j) {
            float lx2 = fmaxf(pb.x, x1[j]), ly2 = fmaxf(pb.y, y1[j]);
            float rx2 = fminf(pb.z, x2[j]), ry2 = fminf(pb.w, y2[j]);
            float iw2 = fmaxf(rx2 - lx2, 0.0f), ih2 = fmaxf(ry2 - ly2, 0.0f);
            float inter2 = iw2 * ih2;
            float iou2 = inter2 / (wax + ar[j] - inter2 + EPS);
            float ie = (lb[j] == plab_) ? iou2 : 0.0f;
            sc[j] *= expf(-(ie * ie) / 0.5f);
        }
        // mark picked (after decay, matching the verified ordering)
#pragma unroll
        for (int j = 0; j < SLOTS; ++j)
            if (lane + (j << 6) == pick) sc[j] = -1.0f;
        if (lane == (pick >> 6)) aw &= ~(1ull << (pick & 63));

        // ---- advance frontier (uniform fast path; shuffle only on overflow) ----
        if (pick == f) {
            if (!slow_ovf) {
                int fn = f + 1;
                bool hit;
                do {
                    hit = (fn == slow[0]) | (fn == slow[1]) | (fn == slow[2]) |
                          (fn == slow[3]) | (fn == slow[4]) | (fn == slow[5]) |
                          (fn == slow[6]) | (fn == slow[7]);
                    if (hit) ++fn;
                } while (hit && fn < TOPK);
                f = fn;
            } else {
                int fw = f >> 6;
                unsigned long long w2 = __shfl(aw, fw);
                while (w2 == 0ull && fw < 15) { ++fw; w2 = __shfl(aw, fw); }
                f = (w2 == 0ull) ? TOPK : (fw << 6) + (__ffsll(w2) - 1);
            }
        } else {
            // record slow pick
            if (nslow < 8) {
#pragma unroll
                for (int i = 0; i < 8; ++i)
                    if (i == nslow) slow[i] = pick;
                ++nslow;
            } else {
                slow_ovf = true;
            }
        }

        // ---- prefetch next-iteration frontier state (overlaps loop backedge) ----
        int fp2 = (f < TOPK) ? f : 0;
        fb = *(const float4*)&s_box[fp2][0];
        flab = s_lab[fp2];
        int fs = f >> 6;
        float v = sc[0];
#pragma unroll
        for (int j = 1; j < SLOTS; ++j) if (fs == j) v = sc[j];
        cf = __shfl(v, f & 63);
    }

    // ---- emit: alive picks in pick order, then dead padding if needed ----
    float* out_boxes  = out;
    float* out_scores = out + (size_t)B * DETS * 4;
    float* out_labels = out + (size_t)B * DETS * 5;
    int kmax = (M + 63) >> 6;
    int base = 0;
    for (int k = 0; k < kmax; ++k) {
        int p = lane + (k << 6);
        bool av = (p < M) && (s_alive[p] != 0);
        unsigned long long mask = __ballot(av);
        int slot = base + (int)__popcll(mask & ((1ull << lane) - 1ull));
        if (av && slot < DETS) {
            float4 pb = *(const float4*)&s_pbox[p][0];
            float* ob = out_boxes + ((size_t)img * DETS + slot) * 4;
            ob[0] = pb.x; ob[1] = pb.y; ob[2] = pb.z; ob[3] = pb.w;
            out_scores[img * DETS + slot] = s_psc[p];
            out_labels[img * DETS + slot] = (float)s_plab[p];
        }
        base += (int)__popcll(mask);
    }
    if (base < DETS) {
        int dbase = 0;
        for (int k = 0; k < kmax; ++k) {
            int p = lane + (k << 6);
            bool dd = (p < M) && (s_alive[p] == 0);
            unsigned long long mask = __ballot(dd);
            int slot = base + dbase + (int)__popcll(mask & ((1ull << lane) - 1ull));
            if (dd && slot < DETS) {
                float4 pb = *(const float4*)&s_pbox[p][0];
                float* ob = out_boxes + ((size_t)img * DETS + slot) * 4;
                ob[0] = pb.x; ob[1] = pb.y; ob[2] = pb.z; ob[3] = pb.w;
                out_scores[img * DETS + slot] = -1.0f;
                out_labels[img * DETS + slot] = (float)s_plab[p];
            }
            dbase += (int)__popcll(mask);
        }
    }
}

extern "C" void kernel_launch(void* const* d_in, const int* in_sizes, int n_in,
                              void* d_out, int out_size, void* d_ws, size_t ws_size,
                              hipStream_t stream) {
    const float* logits = (const float*)d_in[0];
    const float* rel = (const float*)d_in[1];
    const float* anch = (const float*)d_in[2];
    float* out = (float*)d_out;

    int A = in_sizes[2] / 4;                 // anchors
    int B = in_sizes[0] / (A * NCLS);        // batch

    // workspace layout (all 8B-aligned by construction)
    char* w = (char*)d_ws;
    unsigned* hist = (unsigned*)w;           w += (size_t)B * NBINS * 4;   // 18 KB
    unsigned long long* cand = (unsigned long long*)w; w += (size_t)B * CANDMAX * 8;
    unsigned* P = (unsigned*)w;              w += (size_t)B * 4;
    unsigned* ctr = (unsigned*)w;            w += (size_t)B * 4;
    unsigned* top_idx = (unsigned*)w;        w += (size_t)B * TOPK * 4;
    float* top_sc = (float*)w;               w += (size_t)B * TOPK * 4;
    // optional score cache (6.4 MB at B=8, A=200000) if workspace allows
    float* scores = (float*)w;
    size_t used = (size_t)(w - (char*)d_ws);
    int use_scores = (used + (size_t)B * A * 4 <= ws_size) ? 1 : 0;

    hipMemsetAsync(hist, 0, (size_t)B * NBINS * 4, stream);
    hipMemsetAsync(ctr, 0, (size_t)B * 4, stream);

    dim3 g1(NBLK, (unsigned)B);
    k_score_hist<<<g1, 256, 0, stream>>>(logits, scores, hist, A, use_scores);
    k_findP<<<B, 64, 0, stream>>>(hist, P);
    k_compact<<<g1, 256, 0, stream>>>(logits, use_scores ? scores : nullptr, P, ctr, cand, A);
    k_sort<<<B, 1024, 0, stream>>>(cand, ctr, top_idx, top_sc, A);
    k_nms<<<B, 256, 0, stream>>>(logits, rel, anch, top_idx, top_sc, out, A, B);
}

// Round 4
// 387.166 us; speedup vs baseline: 1.1869x; 1.1869x over previous
//
#include <hip/hip_runtime.h>
#include <math.h>

// ---------------- constants from the reference ----------------
#define NCLS 10
#define TOPK 1000
#define DETS 100
#define CANDMAX 4096
#define SLOTS 16   // 16 * 64 lanes = 1024 >= TOPK

// score histogram: scores > 0.05 have (bits>>16) in [0x3D4C, 0x3F80) -> 564 bins
#define BIN0 0x3D4Cu
#define NBINS 576
#define NBLK 64    // blocks per image for the score/compact passes

__device__ __forceinline__ float sigmoidf_(float x) {
    return 1.0f / (1.0f + expf(-x));
}

// K1: fused score + per-block LDS histogram (+ optional score cache).
// score = sigmoid(max(logits)) == max(sigmoid(logits)) (sigmoid monotone).
__global__ __launch_bounds__(256) void k_score_hist(const float* __restrict__ logits,
                                                    float* __restrict__ scores,
                                                    unsigned* __restrict__ hist,
                                                    int A, int use_scores) {
    __shared__ unsigned h[NBINS];
    int img = blockIdx.y;
    for (int i = threadIdx.x; i < NBINS; i += 256) h[i] = 0;
    __syncthreads();

    const float* base = logits + (size_t)img * A * NCLS;
    int nquad = A >> 2;   // 4 anchors (= 40 floats = 10 float4) per iteration
    for (int q = blockIdx.x * 256 + threadIdx.x; q < nquad; q += NBLK * 256) {
        const float4* lp = (const float4*)(base + (size_t)q * 40);
        float f[40];
#pragma unroll
        for (int i = 0; i < 10; ++i) ((float4*)f)[i] = lp[i];
        float4 s4;
        float* sv = &s4.x;
#pragma unroll
        for (int j = 0; j < 4; ++j) {
            float m = f[10 * j];
#pragma unroll
            for (int c = 1; c < 10; ++c) m = fmaxf(m, f[10 * j + c]);
            float sc = sigmoidf_(m);
            sc = (sc > 0.05f) ? sc : 0.0f;
            sv[j] = sc;
            if (sc > 0.0f) {
                unsigned bin = (__float_as_uint(sc) >> 16) - BIN0;
                if (bin >= NBINS) bin = NBINS - 1;   // defensive clamp
                atomicAdd(&h[bin], 1u);
            }
        }
        if (use_scores) ((float4*)(scores + (size_t)img * A))[q] = s4;
    }
    // scalar tail (A % 4), handled by block x==0 of each image
    int tail0 = nquad << 2;
    if (blockIdx.x == 0) {
        for (int a = tail0 + (int)threadIdx.x; a < A; a += 256) {
            const float* lp2 = base + (size_t)a * NCLS;
            float m = lp2[0];
            for (int c = 1; c < 10; ++c) m = fmaxf(m, lp2[c]);
            float sc = sigmoidf_(m);
            sc = (sc > 0.05f) ? sc : 0.0f;
            if (use_scores) scores[(size_t)img * A + a] = sc;
            if (sc > 0.0f) {
                unsigned bin = (__float_as_uint(sc) >> 16) - BIN0;
                if (bin >= NBINS) bin = NBINS - 1;
                atomicAdd(&h[bin], 1u);
            }
        }
    }
    __syncthreads();
    for (int i = threadIdx.x; i < NBINS; i += 256) {
        unsigned c = h[i];
        if (c) atomicAdd(&hist[(size_t)img * NBINS + i], c);
    }
}

// K2: per image, single wave: smallest global bin P with suffix count >= TOPK.
__global__ void k_findP(const unsigned* __restrict__ hist, unsigned* __restrict__ P) {
    int img = blockIdx.x;
    int lane = threadIdx.x;               // 64 threads
    const unsigned* h = hist + (size_t)img * NBINS;
    unsigned b[9];
    unsigned s = 0;
#pragma unroll
    for (int j = 0; j < 9; ++j) { b[j] = h[lane * 9 + j]; s += b[j]; }
    unsigned suf = s;                     // inclusive suffix scan across lanes
#pragma unroll
    for (int d = 1; d < 64; d <<= 1) {
        unsigned o = __shfl_down(suf, d);
        if (lane + d < 64) suf += o;
    }
    unsigned above = __shfl_down(suf, 1);
    if (lane == 63) above = 0;
    if (lane == 0 && suf < (unsigned)TOPK) P[img] = 0u;  // pathological fallback
    if (above < (unsigned)TOPK && suf >= (unsigned)TOPK) {
        unsigned cum = above;
        for (int j = 8; j >= 0; --j) {
            cum += b[j];
            if (cum >= (unsigned)TOPK) { P[img] = BIN0 + (unsigned)(lane * 9 + j); break; }
        }
    }
}

// K3: compact candidates (top16 >= P) with wave-aggregated counter atomics.
__global__ __launch_bounds__(256) void k_compact(const float* __restrict__ logits,
                                                 const float* __restrict__ scores,
                                                 const unsigned* __restrict__ P,
                                                 unsigned* __restrict__ ctr,
                                                 unsigned long long* __restrict__ cand,
                                                 int A) {
    int img = blockIdx.y;
    unsigned p = P[img];
    int lane = threadIdx.x & 63;
    int nquad = A >> 2;
    for (int q = blockIdx.x * 256 + threadIdx.x; q < nquad; q += NBLK * 256) {
        float sv[4];
        if (scores) {
            float4 t = ((const float4*)(scores + (size_t)img * A))[q];
            sv[0] = t.x; sv[1] = t.y; sv[2] = t.z; sv[3] = t.w;
        } else {
            const float* lp = logits + ((size_t)img * A + (size_t)q * 4) * NCLS;
            float f[40];
#pragma unroll
            for (int i = 0; i < 10; ++i) ((float4*)f)[i] = ((const float4*)lp)[i];
#pragma unroll
            for (int j = 0; j < 4; ++j) {
                float m = f[10 * j];
#pragma unroll
                for (int c = 1; c < 10; ++c) m = fmaxf(m, f[10 * j + c]);
                float sc = sigmoidf_(m);
                sv[j] = (sc > 0.05f) ? sc : 0.0f;
            }
        }
#pragma unroll
        for (int j = 0; j < 4; ++j) {
            unsigned bits = __float_as_uint(sv[j]);
            bool take = (bits >> 16) >= p;
            unsigned long long mask = __ballot(take);
            if (mask) {
                int cnt = __popcll(mask);
                int leader = __ffsll((unsigned long long)mask) - 1;
                unsigned pos = 0;
                if (lane == leader) pos = atomicAdd(&ctr[img], (unsigned)cnt);
                pos = (unsigned)__shfl((int)pos, leader);
                if (take) {
                    unsigned slot = pos + (unsigned)__popcll(mask & ((1ull << lane) - 1ull));
                    if (slot < CANDMAX) {
                        unsigned a = (unsigned)(q * 4 + j);
                        cand[(size_t)img * CANDMAX + slot] =
                            ((unsigned long long)bits << 32) | (unsigned)(~a);
                    }
                }
            }
        }
    }
    // scalar tail
    int tail0 = nquad << 2;
    if (blockIdx.x == 0) {
        for (int a = tail0 + (int)threadIdx.x; a < A; a += 256) {
            float sc;
            if (scores) sc = scores[(size_t)img * A + a];
            else {
                const float* lp = logits + ((size_t)img * A + a) * NCLS;
                float m = lp[0];
                for (int c = 1; c < 10; ++c) m = fmaxf(m, lp[c]);
                float s = sigmoidf_(m);
                sc = (s > 0.05f) ? s : 0.0f;
            }
            unsigned bits = __float_as_uint(sc);
            if ((bits >> 16) >= p) {
                unsigned pos = atomicAdd(&ctr[img], 1u);
                if (pos < CANDMAX)
                    cand[(size_t)img * CANDMAX + pos] =
                        ((unsigned long long)bits << 32) | (unsigned)(~a);
            }
        }
    }
}

// K4: per image bitonic sort; adaptive length (n is typically ~1000-1400).
__global__ __launch_bounds__(1024) void k_sort(const unsigned long long* __restrict__ cand,
                                               const unsigned* __restrict__ ctr,
                                               unsigned* __restrict__ top_idx,
                                               float* __restrict__ top_sc, int A) {
    __shared__ unsigned long long key[CANDMAX];
    int img = blockIdx.x;
    unsigned n = ctr[img];
    if (n > CANDMAX) n = CANDMAX;
    int L = (n <= 1024) ? 1024 : (n <= 2048) ? 2048 : CANDMAX;
    for (int i = threadIdx.x; i < L; i += 1024)
        key[i] = (i < (int)n) ? ~cand[(size_t)img * CANDMAX + i] : ~0ull;
    __syncthreads();
    for (int k = 2; k <= L; k <<= 1) {
        for (int j = k >> 1; j > 0; j >>= 1) {
            for (int i = threadIdx.x; i < L; i += 1024) {
                int l = i ^ j;
                if (l > i) {
                    unsigned long long va = key[i], vb = key[l];
                    bool up = ((i & k) == 0);
                    if (up ? (va > vb) : (va < vb)) { key[i] = vb; key[l] = va; }
                }
            }
            __syncthreads();
        }
    }
    for (int t = threadIdx.x; t < TOPK; t += 1024) {
        unsigned long long ik = key[t];           // ik = ~orig
        unsigned idx = (unsigned)ik;              // low 32 of ~orig == original index
        if (idx >= (unsigned)A) idx = 0;          // fault insurance (pathological only)
        top_idx[img * TOPK + t] = idx;
        top_sc[img * TOPK + t] = __uint_as_float(~(unsigned)(ik >> 32));
    }
}

// K5: soft-NMS (frontier fast path) + inline incremental greedy NMS + top-100 emit.
// Round-1 structure (known-good 268us) with exactly two surgical changes:
//  (a) decay ballot-skip: a slot only pays divide+expf when some lane has
//      inter>0 AND matching label (~25% of slots for random boxes); skipped
//      lanes would multiply by expf(-0.0)==1.0f -> bit-identical.
//  (b) early-exit moved BEFORE the decay block (final pick's decay is dead).
__global__ __launch_bounds__(256) void k_nms(const float* __restrict__ logits,
                                             const float* __restrict__ rel,
                                             const float* __restrict__ anch,
                                             const unsigned* __restrict__ top_idx,
                                             const float* __restrict__ top_sc,
                                             float* __restrict__ out, int A, int B) {
    __shared__ float s_box[TOPK][4];
    __shared__ int   s_lab[TOPK];
    __shared__ float s_pbox[TOPK][4];
    __shared__ int   s_plab[TOPK];
    __shared__ float s_psc[TOPK];
    __shared__ int   s_alive[TOPK];

    const float CLIPV = 4.135166556742356f;  // log(1000/16)
    const float EPS = 1e-7f;
    const float W_ = 1333.0f, H_ = 800.0f;

    int img = blockIdx.x;
    int tid = threadIdx.x;

    // ---- Phase A (all 256 threads): decode candidates into LDS ----
    for (int t = tid; t < TOPK; t += 256) {
        unsigned ai = top_idx[img * TOPK + t];
        const float* lp = logits + ((size_t)img * A + ai) * NCLS;
        float best = sigmoidf_(lp[0]); int lbb = 0;
#pragma unroll
        for (int cc = 1; cc < NCLS; ++cc) {
            float v = sigmoidf_(lp[cc]);
            if (v > best) { best = v; lbb = cc; }
        }
        const float* rp = rel + ((size_t)img * A + ai) * 4;
        const float* ap = anch + (size_t)ai * 4;
        float a0 = ap[0], a1 = ap[1], a2 = ap[2], a3 = ap[3];
        float wa = a2 - a0, ha = a3 - a1;
        float cxa = a0 + 0.5f * wa, cya = a1 + 0.5f * ha;
        float dx = rp[0], dy = rp[1];
        float dw = fminf(rp[2], CLIPV), dh = fminf(rp[3], CLIPV);
        float cx = dx * wa + cxa, cy = dy * ha + cya;
        float w = expf(dw) * wa, h = expf(dh) * ha;
        s_box[t][0] = fminf(fmaxf(cx - 0.5f * w, 0.0f), W_);
        s_box[t][1] = fminf(fmaxf(cy - 0.5f * h, 0.0f), H_);
        s_box[t][2] = fminf(fmaxf(cx + 0.5f * w, 0.0f), W_);
        s_box[t][3] = fminf(fmaxf(cy + 0.5f * h, 0.0f), H_);
        s_lab[t] = lbb;
    }
    __syncthreads();
    if (tid >= 64) return;          // wave 0 only from here; no more barriers
    int lane = tid;

    // ---- load 16 slots/lane into registers (static indices only) ----
    float sc[SLOTS], x1[SLOTS], y1[SLOTS], x2[SLOTS], y2[SLOTS], ar[SLOTS];
    int lb[SLOTS];
#pragma unroll
    for (int j = 0; j < SLOTS; ++j) {
        int c = lane + (j << 6);
        if (c < TOPK) {
            float4 bb = *(const float4*)&s_box[c][0];
            x1[j] = bb.x; y1[j] = bb.y; x2[j] = bb.z; y2[j] = bb.w;
            ar[j] = (bb.z - bb.x) * (bb.w - bb.y);
            lb[j] = s_lab[c];
            sc[j] = top_sc[img * TOPK + c];
        } else {
            sc[j] = -2.0f; lb[j] = -1;
            x1[j] = y1[j] = x2[j] = y2[j] = ar[j] = 0.0f;
        }
    }

    // alive-bitmask: lane l (<16) owns indices [64l, 64l+64)
    unsigned long long aw = 0;
    if (lane < 15) aw = ~0ull;
    else if (lane == 15) aw = (1ull << (TOPK - 15 * 64)) - 1;   // 40 bits

    int f = 0;            // frontier: lowest unpicked index
    int nconf = 0;        // confirmed greedy-alive detections
    int M = TOPK;

    for (int t = 0; t < TOPK; ++t) {
        int fp = (f < TOPK) ? f : 0;
        // prefetch frontier box/label (immutable LDS, broadcast reads)
        float4 fb = *(const float4*)&s_box[fp][0];
        int flab = s_lab[fp];
        // frontier current score: static-select slot (f>>6) then shfl from owner
        int fs = f >> 6;
        float v = sc[0];
#pragma unroll
        for (int j = 1; j < SLOTS; ++j) if (fs == j) v = sc[j];
        float cf = __shfl(v, f & 63);
        // per-lane max over slots
        float lm = sc[0];
#pragma unroll
        for (int j = 1; j < SLOTS; ++j) lm = fmaxf(lm, sc[j]);

        int pick; float pcur; float4 pb; int plab_;
        unsigned long long bb = __ballot(lm > cf);
        if (bb == 0) {
            // common path: frontier is the global argmax (ties -> lowest index = f)
            pick = f; pcur = cf; pb = fb; plab_ = flab;
        } else {
            // rare path: full argmax reduce (value desc, index asc)
            float bv = sc[0]; int bi = lane;
#pragma unroll
            for (int j = 1; j < SLOTS; ++j) {
                int e = lane + (j << 6);
                if (sc[j] > bv) { bv = sc[j]; bi = e; }
            }
#pragma unroll
            for (int d = 32; d; d >>= 1) {
                float ov = __shfl_xor(bv, d);
                int oi = __shfl_xor(bi, d);
                if (ov > bv || (ov == bv && oi < bi)) { bv = ov; bi = oi; }
            }
            pick = bi; pcur = bv;
            pb = *(const float4*)&s_box[pick][0];
            plab_ = s_lab[pick];
        }

        float psc = fmaxf(pcur, 0.0f);
        if (lane == 0) {
            *(float4*)&s_pbox[t][0] = pb;
            s_plab[t] = plab_;
            s_psc[t] = psc;
        }

        // ---- inline greedy survival of pick t (vs earlier ALIVE picks) ----
        bool alive = (psc > 0.3f);
        if (alive && t > 0) {
            float pa = (pb.z - pb.x) * (pb.w - pb.y);
            int kprev = ((t - 1) >> 6) + 1;
            bool sup = false;
            for (int k = 0; k < kprev; ++k) {
                int p = lane + (k << 6);
                int pc = (p < t) ? p : 0;
                float4 qb = *(const float4*)&s_pbox[pc][0];
                int ga = s_alive[pc];
                if (p < t && ga) {
                    float lx = fmaxf(pb.x, qb.x), ly = fmaxf(pb.y, qb.y);
                    float rx = fminf(pb.z, qb.z), ry = fminf(pb.w, qb.w);
                    float iw = fmaxf(rx - lx, 0.0f), ih = fmaxf(ry - ly, 0.0f);
                    float inter = iw * ih;
                    float qa = (qb.z - qb.x) * (qb.w - qb.y);
                    float iou = inter / (pa + qa - inter + EPS);
                    sup = sup || (iou > 0.8f);
                }
            }
            alive = (__ballot(sup) == 0ull);
        }
        if (lane == 0) s_alive[t] = alive ? 1 : 0;
        nconf += alive ? 1 : 0;
        if (nconf >= DETS) { M = t + 1; break; }   // exit BEFORE dead decay work

        // ---- decay (ballot-skip: divide+expf only when a lane is "hot") ----
        float wax = (pb.z - pb.x) * (pb.w - pb.y);
#pragma unroll
        for (int j = 0; j < SLOTS; ++j) {
            float lx2 = fmaxf(pb.x, x1[j]), ly2 = fmaxf(pb.y, y1[j]);
            float rx2 = fminf(pb.z, x2[j]), ry2 = fminf(pb.w, y2[j]);
            float iw2 = fmaxf(rx2 - lx2, 0.0f), ih2 = fmaxf(ry2 - ly2, 0.0f);
            float inter2 = iw2 * ih2;
            bool hot = (inter2 > 0.0f) && (lb[j] == plab_);
            if (__ballot(hot) != 0ull) {
                float iou2 = inter2 / (wax + ar[j] - inter2 + EPS);
                float ie = (lb[j] == plab_) ? iou2 : 0.0f;
                sc[j] *= expf(-(ie * ie) / 0.5f);
            }
            // skipped slots/lanes: factor would be expf(-0.0f) == 1.0f exactly
        }
        // mark picked (after decay, matching the verified ordering)
#pragma unroll
        for (int j = 0; j < SLOTS; ++j)
            if (lane + (j << 6) == pick) sc[j] = -1.0f;
        if (lane == (pick >> 6)) aw &= ~(1ull << (pick & 63));

        // advance frontier
        if (pick == f) {
            int fw = f >> 6;
            unsigned long long w2 = __shfl(aw, fw);
            while (w2 == 0ull && fw < 15) { ++fw; w2 = __shfl(aw, fw); }
            f = (w2 == 0ull) ? TOPK : (fw << 6) + (__ffsll(w2) - 1);
        }
    }

    // ---- emit: alive picks in pick order, then dead padding if needed ----
    float* out_boxes  = out;
    float* out_scores = out + (size_t)B * DETS * 4;
    float* out_labels = out + (size_t)B * DETS * 5;
    int kmax = (M + 63) >> 6;
    int base = 0;
    for (int k = 0; k < kmax; ++k) {
        int p = lane + (k << 6);
        bool av = (p < M) && (s_alive[p] != 0);
        unsigned long long mask = __ballot(av);
        int slot = base + (int)__popcll(mask & ((1ull << lane) - 1ull));
        if (av && slot < DETS) {
            float4 pb = *(const float4*)&s_pbox[p][0];
            float* ob = out_boxes + ((size_t)img * DETS + slot) * 4;
            ob[0] = pb.x; ob[1] = pb.y; ob[2] = pb.z; ob[3] = pb.w;
            out_scores[img * DETS + slot] = s_psc[p];
            out_labels[img * DETS + slot] = (float)s_plab[p];
        }
        base += (int)__popcll(mask);
    }
    if (base < DETS) {
        int dbase = 0;
        for (int k = 0; k < kmax; ++k) {
            int p = lane + (k << 6);
            bool dd = (p < M) && (s_alive[p] == 0);
            unsigned long long mask = __ballot(dd);
            int slot = base + dbase + (int)__popcll(mask & ((1ull << lane) - 1ull));
            if (dd && slot < DETS) {
                float4 pb = *(const float4*)&s_pbox[p][0];
                float* ob = out_boxes + ((size_t)img * DETS + slot) * 4;
                ob[0] = pb.x; ob[1] = pb.y; ob[2] = pb.z; ob[3] = pb.w;
                out_scores[img * DETS + slot] = -1.0f;
                out_labels[img * DETS + slot] = (float)s_plab[p];
            }
            dbase += (int)__popcll(mask);
        }
    }
}

extern "C" void kernel_launch(void* const* d_in, const int* in_sizes, int n_in,
                              void* d_out, int out_size, void* d_ws, size_t ws_size,
                              hipStream_t stream) {
    const float* logits = (const float*)d_in[0];
    const float* rel = (const float*)d_in[1];
    const float* anch = (const float*)d_in[2];
    float* out = (float*)d_out;

    int A = in_sizes[2] / 4;                 // anchors
    int B = in_sizes[0] / (A * NCLS);        // batch

    // workspace layout (all 8B-aligned by construction)
    char* w = (char*)d_ws;
    unsigned* hist = (unsigned*)w;           w += (size_t)B * NBINS * 4;   // 18 KB
    unsigned long long* cand = (unsigned long long*)w; w += (size_t)B * CANDMAX * 8;
    unsigned* P = (unsigned*)w;              w += (size_t)B * 4;
    unsigned* ctr = (unsigned*)w;            w += (size_t)B * 4;
    unsigned* top_idx = (unsigned*)w;        w += (size_t)B * TOPK * 4;
    float* top_sc = (float*)w;               w += (size_t)B * TOPK * 4;
    // optional score cache (6.4 MB at B=8, A=200000) if workspace allows
    float* scores = (float*)w;
    size_t used = (size_t)(w - (char*)d_ws);
    int use_scores = (used + (size_t)B * A * 4 <= ws_size) ? 1 : 0;

    hipMemsetAsync(hist, 0, (size_t)B * NBINS * 4, stream);
    hipMemsetAsync(ctr, 0, (size_t)B * 4, stream);

    dim3 g1(NBLK, (unsigned)B);
    k_score_hist<<<g1, 256, 0, stream>>>(logits, scores, hist, A, use_scores);
    k_findP<<<B, 64, 0, stream>>>(hist, P);
    k_compact<<<g1, 256, 0, stream>>>(logits, use_scores ? scores : nullptr, P, ctr, cand, A);
    k_sort<<<B, 1024, 0, stream>>>(cand, ctr, top_idx, top_sc, A);
    k_nms<<<B, 256, 0, stream>>>(logits, rel, anch, top_idx, top_sc, out, A, B);
}

// Round 5
// 300.225 us; speedup vs baseline: 1.5306x; 1.2896x over previous
//
#include <hip/hip_runtime.h>
#include <math.h>

// ---------------- constants from the reference ----------------
#define NCLS 10
#define TOPK 1000
#define DETS 100
#define CANDMAX 4096
#define SLOTS 16   // 16 * 64 lanes = 1024 >= TOPK
#define ACTK 256   // fast-path active set: 4 slots * 64 lanes

// score histogram: scores > 0.05 have (bits>>16) in [0x3D4C, 0x3F80) -> 564 bins
#define BIN0 0x3D4Cu
#define NBINS 576
#define NBLK 64    // blocks per image for the score/compact passes

__device__ __forceinline__ float sigmoidf_(float x) {
    return 1.0f / (1.0f + expf(-x));
}

// K1: fused score + per-block LDS histogram (+ optional score cache).
// score = sigmoid(max(logits)) == max(sigmoid(logits)) (sigmoid monotone).
__global__ __launch_bounds__(256) void k_score_hist(const float* __restrict__ logits,
                                                    float* __restrict__ scores,
                                                    unsigned* __restrict__ hist,
                                                    int A, int use_scores) {
    __shared__ unsigned h[NBINS];
    int img = blockIdx.y;
    for (int i = threadIdx.x; i < NBINS; i += 256) h[i] = 0;
    __syncthreads();

    const float* base = logits + (size_t)img * A * NCLS;
    int nquad = A >> 2;   // 4 anchors (= 40 floats = 10 float4) per iteration
    for (int q = blockIdx.x * 256 + threadIdx.x; q < nquad; q += NBLK * 256) {
        const float4* lp = (const float4*)(base + (size_t)q * 40);
        float f[40];
#pragma unroll
        for (int i = 0; i < 10; ++i) ((float4*)f)[i] = lp[i];
        float4 s4;
        float* sv = &s4.x;
#pragma unroll
        for (int j = 0; j < 4; ++j) {
            float m = f[10 * j];
#pragma unroll
            for (int c = 1; c < 10; ++c) m = fmaxf(m, f[10 * j + c]);
            float sc = sigmoidf_(m);
            sc = (sc > 0.05f) ? sc : 0.0f;
            sv[j] = sc;
            if (sc > 0.0f) {
                unsigned bin = (__float_as_uint(sc) >> 16) - BIN0;
                if (bin >= NBINS) bin = NBINS - 1;   // defensive clamp
                atomicAdd(&h[bin], 1u);
            }
        }
        if (use_scores) ((float4*)(scores + (size_t)img * A))[q] = s4;
    }
    // scalar tail (A % 4), handled by block x==0 of each image
    int tail0 = nquad << 2;
    if (blockIdx.x == 0) {
        for (int a = tail0 + (int)threadIdx.x; a < A; a += 256) {
            const float* lp2 = base + (size_t)a * NCLS;
            float m = lp2[0];
            for (int c = 1; c < 10; ++c) m = fmaxf(m, lp2[c]);
            float sc = sigmoidf_(m);
            sc = (sc > 0.05f) ? sc : 0.0f;
            if (use_scores) scores[(size_t)img * A + a] = sc;
            if (sc > 0.0f) {
                unsigned bin = (__float_as_uint(sc) >> 16) - BIN0;
                if (bin >= NBINS) bin = NBINS - 1;
                atomicAdd(&h[bin], 1u);
            }
        }
    }
    __syncthreads();
    for (int i = threadIdx.x; i < NBINS; i += 256) {
        unsigned c = h[i];
        if (c) atomicAdd(&hist[(size_t)img * NBINS + i], c);
    }
}

// K2: per image, single wave: smallest global bin P with suffix count >= TOPK.
__global__ void k_findP(const unsigned* __restrict__ hist, unsigned* __restrict__ P) {
    int img = blockIdx.x;
    int lane = threadIdx.x;               // 64 threads
    const unsigned* h = hist + (size_t)img * NBINS;
    unsigned b[9];
    unsigned s = 0;
#pragma unroll
    for (int j = 0; j < 9; ++j) { b[j] = h[lane * 9 + j]; s += b[j]; }
    unsigned suf = s;                     // inclusive suffix scan across lanes
#pragma unroll
    for (int d = 1; d < 64; d <<= 1) {
        unsigned o = __shfl_down(suf, d);
        if (lane + d < 64) suf += o;
    }
    unsigned above = __shfl_down(suf, 1);
    if (lane == 63) above = 0;
    if (lane == 0 && suf < (unsigned)TOPK) P[img] = 0u;  // pathological fallback
    if (above < (unsigned)TOPK && suf >= (unsigned)TOPK) {
        unsigned cum = above;
        for (int j = 8; j >= 0; --j) {
            cum += b[j];
            if (cum >= (unsigned)TOPK) { P[img] = BIN0 + (unsigned)(lane * 9 + j); break; }
        }
    }
}

// K3: compact candidates (top16 >= P) with wave-aggregated counter atomics.
__global__ __launch_bounds__(256) void k_compact(const float* __restrict__ logits,
                                                 const float* __restrict__ scores,
                                                 const unsigned* __restrict__ P,
                                                 unsigned* __restrict__ ctr,
                                                 unsigned long long* __restrict__ cand,
                                                 int A) {
    int img = blockIdx.y;
    unsigned p = P[img];
    int lane = threadIdx.x & 63;
    int nquad = A >> 2;
    for (int q = blockIdx.x * 256 + threadIdx.x; q < nquad; q += NBLK * 256) {
        float sv[4];
        if (scores) {
            float4 t = ((const float4*)(scores + (size_t)img * A))[q];
            sv[0] = t.x; sv[1] = t.y; sv[2] = t.z; sv[3] = t.w;
        } else {
            const float* lp = logits + ((size_t)img * A + (size_t)q * 4) * NCLS;
            float f[40];
#pragma unroll
            for (int i = 0; i < 10; ++i) ((float4*)f)[i] = ((const float4*)lp)[i];
#pragma unroll
            for (int j = 0; j < 4; ++j) {
                float m = f[10 * j];
#pragma unroll
                for (int c = 1; c < 10; ++c) m = fmaxf(m, f[10 * j + c]);
                float sc = sigmoidf_(m);
                sv[j] = (sc > 0.05f) ? sc : 0.0f;
            }
        }
#pragma unroll
        for (int j = 0; j < 4; ++j) {
            unsigned bits = __float_as_uint(sv[j]);
            bool take = (bits >> 16) >= p;
            unsigned long long mask = __ballot(take);
            if (mask) {
                int cnt = __popcll(mask);
                int leader = __ffsll((unsigned long long)mask) - 1;
                unsigned pos = 0;
                if (lane == leader) pos = atomicAdd(&ctr[img], (unsigned)cnt);
                pos = (unsigned)__shfl((int)pos, leader);
                if (take) {
                    unsigned slot = pos + (unsigned)__popcll(mask & ((1ull << lane) - 1ull));
                    if (slot < CANDMAX) {
                        unsigned a = (unsigned)(q * 4 + j);
                        cand[(size_t)img * CANDMAX + slot] =
                            ((unsigned long long)bits << 32) | (unsigned)(~a);
                    }
                }
            }
        }
    }
    // scalar tail
    int tail0 = nquad << 2;
    if (blockIdx.x == 0) {
        for (int a = tail0 + (int)threadIdx.x; a < A; a += 256) {
            float sc;
            if (scores) sc = scores[(size_t)img * A + a];
            else {
                const float* lp = logits + ((size_t)img * A + a) * NCLS;
                float m = lp[0];
                for (int c = 1; c < 10; ++c) m = fmaxf(m, lp[c]);
                float s = sigmoidf_(m);
                sc = (s > 0.05f) ? s : 0.0f;
            }
            unsigned bits = __float_as_uint(sc);
            if ((bits >> 16) >= p) {
                unsigned pos = atomicAdd(&ctr[img], 1u);
                if (pos < CANDMAX)
                    cand[(size_t)img * CANDMAX + pos] =
                        ((unsigned long long)bits << 32) | (unsigned)(~a);
            }
        }
    }
}

// K4: per image bitonic sort; adaptive length (n is typically ~1000-1400).
__global__ __launch_bounds__(1024) void k_sort(const unsigned long long* __restrict__ cand,
                                               const unsigned* __restrict__ ctr,
                                               unsigned* __restrict__ top_idx,
                                               float* __restrict__ top_sc, int A) {
    __shared__ unsigned long long key[CANDMAX];
    int img = blockIdx.x;
    unsigned n = ctr[img];
    if (n > CANDMAX) n = CANDMAX;
    int L = (n <= 1024) ? 1024 : (n <= 2048) ? 2048 : CANDMAX;
    for (int i = threadIdx.x; i < L; i += 1024)
        key[i] = (i < (int)n) ? ~cand[(size_t)img * CANDMAX + i] : ~0ull;
    __syncthreads();
    for (int k = 2; k <= L; k <<= 1) {
        for (int j = k >> 1; j > 0; j >>= 1) {
            for (int i = threadIdx.x; i < L; i += 1024) {
                int l = i ^ j;
                if (l > i) {
                    unsigned long long va = key[i], vb = key[l];
                    bool up = ((i & k) == 0);
                    if (up ? (va > vb) : (va < vb)) { key[i] = vb; key[l] = va; }
                }
            }
            __syncthreads();
        }
    }
    for (int t = threadIdx.x; t < TOPK; t += 1024) {
        unsigned long long ik = key[t];           // ik = ~orig
        unsigned idx = (unsigned)ik;              // low 32 of ~orig == original index
        if (idx >= (unsigned)A) idx = 0;          // fault insurance (pathological only)
        top_idx[img * TOPK + t] = idx;
        top_sc[img * TOPK + t] = __uint_as_float(~(unsigned)(ik >> 32));
    }
}

// K5: soft-NMS + greedy NMS + top-100 emit.
// FAST ATTEMPT over the top-256 candidates only (4 slots/lane), exact via the
// active-set bound: scores only decay, so any candidate outside the active set
// has current score <= its initial score <= top_sc[256]. As long as each pick's
// decayed score pcur >= top_sc[256], the global argmax provably lies in the
// active set (ties break to lower sorted index = active, matching argmax).
// If the guard ever fails, or 256 picks yield <100 detections, rerun the
// proven full 16-slot loop from the intact initial state.
__global__ __launch_bounds__(256) void k_nms(const float* __restrict__ logits,
                                             const float* __restrict__ rel,
                                             const float* __restrict__ anch,
                                             const unsigned* __restrict__ top_idx,
                                             const float* __restrict__ top_sc,
                                             float* __restrict__ out, int A, int B) {
    __shared__ float s_box[TOPK][4];
    __shared__ int   s_lab[TOPK];
    __shared__ float s_pbox[TOPK][4];
    __shared__ int   s_plab[TOPK];
    __shared__ float s_psc[TOPK];
    __shared__ int   s_alive[TOPK];

    const float CLIPV = 4.135166556742356f;  // log(1000/16)
    const float EPS = 1e-7f;
    const float W_ = 1333.0f, H_ = 800.0f;

    int img = blockIdx.x;
    int tid = threadIdx.x;

    // ---- Phase A (all 256 threads): decode candidates into LDS ----
    for (int t = tid; t < TOPK; t += 256) {
        unsigned ai = top_idx[img * TOPK + t];
        const float* lp = logits + ((size_t)img * A + ai) * NCLS;
        float best = sigmoidf_(lp[0]); int lbb = 0;
#pragma unroll
        for (int cc = 1; cc < NCLS; ++cc) {
            float v = sigmoidf_(lp[cc]);
            if (v > best) { best = v; lbb = cc; }
        }
        const float* rp = rel + ((size_t)img * A + ai) * 4;
        const float* ap = anch + (size_t)ai * 4;
        float a0 = ap[0], a1 = ap[1], a2 = ap[2], a3 = ap[3];
        float wa = a2 - a0, ha = a3 - a1;
        float cxa = a0 + 0.5f * wa, cya = a1 + 0.5f * ha;
        float dx = rp[0], dy = rp[1];
        float dw = fminf(rp[2], CLIPV), dh = fminf(rp[3], CLIPV);
        float cx = dx * wa + cxa, cy = dy * ha + cya;
        float w = expf(dw) * wa, h = expf(dh) * ha;
        s_box[t][0] = fminf(fmaxf(cx - 0.5f * w, 0.0f), W_);
        s_box[t][1] = fminf(fmaxf(cy - 0.5f * h, 0.0f), H_);
        s_box[t][2] = fminf(fmaxf(cx + 0.5f * w, 0.0f), W_);
        s_box[t][3] = fminf(fmaxf(cy + 0.5f * h, 0.0f), H_);
        s_lab[t] = lbb;
    }
    __syncthreads();
    if (tid >= 64) return;          // wave 0 only from here; no more barriers
    int lane = tid;

    int M = TOPK;
    int need_full = 0;
    float bound = top_sc[img * TOPK + ACTK];   // init score of first EXCLUDED cand

    // ================= FAST ATTEMPT: 4 slots / 256 candidates =================
    {
        float sc[4], x1[4], y1[4], x2[4], y2[4], ar[4];
        int lb[4];
#pragma unroll
        for (int j = 0; j < 4; ++j) {
            int c = lane + (j << 6);
            float4 bb = *(const float4*)&s_box[c][0];
            x1[j] = bb.x; y1[j] = bb.y; x2[j] = bb.z; y2[j] = bb.w;
            ar[j] = (bb.z - bb.x) * (bb.w - bb.y);
            lb[j] = s_lab[c];
            sc[j] = top_sc[img * TOPK + c];
        }

        unsigned long long aw = (lane < 4) ? ~0ull : 0ull;
        int f = 0, nconf = 0, Mf = -1;

        for (int t = 0; t < ACTK; ++t) {
            // frontier state (f <= t < 256 always: picks so far = t)
            float4 fb = *(const float4*)&s_box[f][0];
            int flab = s_lab[f];
            int fs = f >> 6;
            float v = sc[0];
            if (fs == 1) v = sc[1];
            if (fs == 2) v = sc[2];
            if (fs == 3) v = sc[3];
            float cf = __shfl(v, f & 63);
            float lm = fmaxf(fmaxf(sc[0], sc[1]), fmaxf(sc[2], sc[3]));

            int pick; float pcur; float4 pb; int plab_;
            unsigned long long bb2 = __ballot(lm > cf);
            if (bb2 == 0) {
                pick = f; pcur = cf; pb = fb; plab_ = flab;
            } else {
                float bv = sc[0]; int bi = lane;
#pragma unroll
                for (int j = 1; j < 4; ++j) {
                    int e = lane + (j << 6);
                    if (sc[j] > bv) { bv = sc[j]; bi = e; }
                }
#pragma unroll
                for (int d = 32; d; d >>= 1) {
                    float ov = __shfl_xor(bv, d);
                    int oi = __shfl_xor(bi, d);
                    if (ov > bv || (ov == bv && oi < bi)) { bv = ov; bi = oi; }
                }
                pick = bi; pcur = bv;
                pb = *(const float4*)&s_box[pick][0];
                plab_ = s_lab[pick];
            }

            // active-set guard (uniform): excluded cands all have score <= bound
            if (!(pcur >= bound)) { need_full = 1; break; }

            float psc = fmaxf(pcur, 0.0f);
            if (lane == 0) {
                *(float4*)&s_pbox[t][0] = pb;
                s_plab[t] = plab_;
                s_psc[t] = psc;
            }

            // greedy survival vs earlier ALIVE picks
            bool alive = (psc > 0.3f);
            if (alive && t > 0) {
                float pa = (pb.z - pb.x) * (pb.w - pb.y);
                int kprev = ((t - 1) >> 6) + 1;
                bool sup = false;
                for (int k = 0; k < kprev; ++k) {
                    int p = lane + (k << 6);
                    int pc = (p < t) ? p : 0;
                    float4 qb = *(const float4*)&s_pbox[pc][0];
                    int ga = s_alive[pc];
                    if (p < t && ga) {
                        float lx = fmaxf(pb.x, qb.x), ly = fmaxf(pb.y, qb.y);
                        float rx = fminf(pb.z, qb.z), ry = fminf(pb.w, qb.w);
                        float iw = fmaxf(rx - lx, 0.0f), ih = fmaxf(ry - ly, 0.0f);
                        float inter = iw * ih;
                        float qa = (qb.z - qb.x) * (qb.w - qb.y);
                        float iou = inter / (pa + qa - inter + EPS);
                        sup = sup || (iou > 0.8f);
                    }
                }
                alive = (__ballot(sup) == 0ull);
            }
            if (lane == 0) s_alive[t] = alive ? 1 : 0;
            nconf += alive ? 1 : 0;
            if (nconf >= DETS) { Mf = t + 1; break; }

            // decay (ballot-skip: divide+expf only when a lane is "hot")
            float wax = (pb.z - pb.x) * (pb.w - pb.y);
#pragma unroll
            for (int j = 0; j < 4; ++j) {
                float lx2 = fmaxf(pb.x, x1[j]), ly2 = fmaxf(pb.y, y1[j]);
                float rx2 = fminf(pb.z, x2[j]), ry2 = fminf(pb.w, y2[j]);
                float iw2 = fmaxf(rx2 - lx2, 0.0f), ih2 = fmaxf(ry2 - ly2, 0.0f);
                float inter2 = iw2 * ih2;
                bool hot = (inter2 > 0.0f) && (lb[j] == plab_);
                if (__ballot(hot) != 0ull) {
                    float iou2 = inter2 / (wax + ar[j] - inter2 + EPS);
                    float ie = (lb[j] == plab_) ? iou2 : 0.0f;
                    sc[j] *= expf(-(ie * ie) / 0.5f);
                }
            }
            // mark picked
#pragma unroll
            for (int j = 0; j < 4; ++j)
                if (lane + (j << 6) == pick) sc[j] = -1.0f;
            if (lane == (pick >> 6)) aw &= ~(1ull << (pick & 63));

            // advance frontier
            if (pick == f) {
                int fw = f >> 6;
                unsigned long long w2 = __shfl(aw, fw);
                while (w2 == 0ull && fw < 3) { ++fw; w2 = __shfl(aw, fw); }
                f = (w2 == 0ull) ? ACTK : (fw << 6) + (__ffsll(w2) - 1);
            }
        }
        if (!need_full) {
            if (Mf < 0) need_full = 1;   // exhausted 256 picks with <100 dets
            else M = Mf;
        }
    }

    // ================= FULL FALLBACK: verbatim 16-slot loop =================
    if (need_full) {
        float sc[SLOTS], x1[SLOTS], y1[SLOTS], x2[SLOTS], y2[SLOTS], ar[SLOTS];
        int lb[SLOTS];
#pragma unroll
        for (int j = 0; j < SLOTS; ++j) {
            int c = lane + (j << 6);
            if (c < TOPK) {
                float4 bb = *(const float4*)&s_box[c][0];
                x1[j] = bb.x; y1[j] = bb.y; x2[j] = bb.z; y2[j] = bb.w;
                ar[j] = (bb.z - bb.x) * (bb.w - bb.y);
                lb[j] = s_lab[c];
                sc[j] = top_sc[img * TOPK + c];
            } else {
                sc[j] = -2.0f; lb[j] = -1;
                x1[j] = y1[j] = x2[j] = y2[j] = ar[j] = 0.0f;
            }
        }

        unsigned long long aw = 0;
        if (lane < 15) aw = ~0ull;
        else if (lane == 15) aw = (1ull << (TOPK - 15 * 64)) - 1;   // 40 bits

        int f = 0, nconf = 0;
        M = TOPK;

        for (int t = 0; t < TOPK; ++t) {
            int fp = (f < TOPK) ? f : 0;
            float4 fb = *(const float4*)&s_box[fp][0];
            int flab = s_lab[fp];
            int fs = f >> 6;
            float v = sc[0];
#pragma unroll
            for (int j = 1; j < SLOTS; ++j) if (fs == j) v = sc[j];
            float cf = __shfl(v, f & 63);
            float lm = sc[0];
#pragma unroll
            for (int j = 1; j < SLOTS; ++j) lm = fmaxf(lm, sc[j]);

            int pick; float pcur; float4 pb; int plab_;
            unsigned long long bb2 = __ballot(lm > cf);
            if (bb2 == 0) {
                pick = f; pcur = cf; pb = fb; plab_ = flab;
            } else {
                float bv = sc[0]; int bi = lane;
#pragma unroll
                for (int j = 1; j < SLOTS; ++j) {
                    int e = lane + (j << 6);
                    if (sc[j] > bv) { bv = sc[j]; bi = e; }
                }
#pragma unroll
                for (int d = 32; d; d >>= 1) {
                    float ov = __shfl_xor(bv, d);
                    int oi = __shfl_xor(bi, d);
                    if (ov > bv || (ov == bv && oi < bi)) { bv = ov; bi = oi; }
                }
                pick = bi; pcur = bv;
                pb = *(const float4*)&s_box[pick][0];
                plab_ = s_lab[pick];
            }

            float psc = fmaxf(pcur, 0.0f);
            if (lane == 0) {
                *(float4*)&s_pbox[t][0] = pb;
                s_plab[t] = plab_;
                s_psc[t] = psc;
            }

            bool alive = (psc > 0.3f);
            if (alive && t > 0) {
                float pa = (pb.z - pb.x) * (pb.w - pb.y);
                int kprev = ((t - 1) >> 6) + 1;
                bool sup = false;
                for (int k = 0; k < kprev; ++k) {
                    int p = lane + (k << 6);
                    int pc = (p < t) ? p : 0;
                    float4 qb = *(const float4*)&s_pbox[pc][0];
                    int ga = s_alive[pc];
                    if (p < t && ga) {
                        float lx = fmaxf(pb.x, qb.x), ly = fmaxf(pb.y, qb.y);
                        float rx = fminf(pb.z, qb.z), ry = fminf(pb.w, qb.w);
                        float iw = fmaxf(rx - lx, 0.0f), ih = fmaxf(ry - ly, 0.0f);
                        float inter = iw * ih;
                        float qa = (qb.z - qb.x) * (qb.w - qb.y);
                        float iou = inter / (pa + qa - inter + EPS);
                        sup = sup || (iou > 0.8f);
                    }
                }
                alive = (__ballot(sup) == 0ull);
            }
            if (lane == 0) s_alive[t] = alive ? 1 : 0;
            nconf += alive ? 1 : 0;
            if (nconf >= DETS) { M = t + 1; break; }

            float wax = (pb.z - pb.x) * (pb.w - pb.y);
#pragma unroll
            for (int j = 0; j < SLOTS; ++j) {
                float lx2 = fmaxf(pb.x, x1[j]), ly2 = fmaxf(pb.y, y1[j]);
                float rx2 = fminf(pb.z, x2[j]), ry2 = fminf(pb.w, y2[j]);
                float iw2 = fmaxf(rx2 - lx2, 0.0f), ih2 = fmaxf(ry2 - ly2, 0.0f);
                float inter2 = iw2 * ih2;
                bool hot = (inter2 > 0.0f) && (lb[j] == plab_);
                if (__ballot(hot) != 0ull) {
                    float iou2 = inter2 / (wax + ar[j] - inter2 + EPS);
                    float ie = (lb[j] == plab_) ? iou2 : 0.0f;
                    sc[j] *= expf(-(ie * ie) / 0.5f);
                }
            }
#pragma unroll
            for (int j = 0; j < SLOTS; ++j)
                if (lane + (j << 6) == pick) sc[j] = -1.0f;
            if (lane == (pick >> 6)) aw &= ~(1ull << (pick & 63));

            if (pick == f) {
                int fw = f >> 6;
                unsigned long long w2 = __shfl(aw, fw);
                while (w2 == 0ull && fw < 15) { ++fw; w2 = __shfl(aw, fw); }
                f = (w2 == 0ull) ? TOPK : (fw << 6) + (__ffsll(w2) - 1);
            }
        }
    }

    // ---- emit: alive picks in pick order, then dead padding if needed ----
    float* out_boxes  = out;
    float* out_scores = out + (size_t)B * DETS * 4;
    float* out_labels = out + (size_t)B * DETS * 5;
    int kmax = (M + 63) >> 6;
    int base = 0;
    for (int k = 0; k < kmax; ++k) {
        int p = lane + (k << 6);
        bool av = (p < M) && (s_alive[p] != 0);
        unsigned long long mask = __ballot(av);
        int slot = base + (int)__popcll(mask & ((1ull << lane) - 1ull));
        if (av && slot < DETS) {
            float4 pb = *(const float4*)&s_pbox[p][0];
            float* ob = out_boxes + ((size_t)img * DETS + slot) * 4;
            ob[0] = pb.x; ob[1] = pb.y; ob[2] = pb.z; ob[3] = pb.w;
            out_scores[img * DETS + slot] = s_psc[p];
            out_labels[img * DETS + slot] = (float)s_plab[p];
        }
        base += (int)__popcll(mask);
    }
    if (base < DETS) {
        int dbase = 0;
        for (int k = 0; k < kmax; ++k) {
            int p = lane + (k << 6);
            bool dd = (p < M) && (s_alive[p] == 0);
            unsigned long long mask = __ballot(dd);
            int slot = base + dbase + (int)__popcll(mask & ((1ull << lane) - 1ull));
            if (dd && slot < DETS) {
                float4 pb = *(const float4*)&s_pbox[p][0];
                float* ob = out_boxes + ((size_t)img * DETS + slot) * 4;
                ob[0] = pb.x; ob[1] = pb.y; ob[2] = pb.z; ob[3] = pb.w;
                out_scores[img * DETS + slot] = -1.0f;
                out_labels[img * DETS + slot] = (float)s_plab[p];
            }
            dbase += (int)__popcll(mask);
        }
    }
}

extern "C" void kernel_launch(void* const* d_in, const int* in_sizes, int n_in,
                              void* d_out, int out_size, void* d_ws, size_t ws_size,
                              hipStream_t stream) {
    const float* logits = (const float*)d_in[0];
    const float* rel = (const float*)d_in[1];
    const float* anch = (const float*)d_in[2];
    float* out = (float*)d_out;

    int A = in_sizes[2] / 4;                 // anchors
    int B = in_sizes[0] / (A * NCLS);        // batch

    // workspace layout (all 8B-aligned by construction)
    char* w = (char*)d_ws;
    unsigned* hist = (unsigned*)w;           w += (size_t)B * NBINS * 4;   // 18 KB
    unsigned long long* cand = (unsigned long long*)w; w += (size_t)B * CANDMAX * 8;
    unsigned* P = (unsigned*)w;              w += (size_t)B * 4;
    unsigned* ctr = (unsigned*)w;            w += (size_t)B * 4;
    unsigned* top_idx = (unsigned*)w;        w += (size_t)B * TOPK * 4;
    float* top_sc = (float*)w;               w += (size_t)B * TOPK * 4;
    // optional score cache (6.4 MB at B=8, A=200000) if workspace allows
    float* scores = (float*)w;
    size_t used = (size_t)(w - (char*)d_ws);
    int use_scores = (used + (size_t)B * A * 4 <= ws_size) ? 1 : 0;

    hipMemsetAsync(hist, 0, (size_t)B * NBINS * 4, stream);
    hipMemsetAsync(ctr, 0, (size_t)B * 4, stream);

    dim3 g1(NBLK, (unsigned)B);
    k_score_hist<<<g1, 256, 0, stream>>>(logits, scores, hist, A, use_scores);
    k_findP<<<B, 64, 0, stream>>>(hist, P);
    k_compact<<<g1, 256, 0, stream>>>(logits, use_scores ? scores : nullptr, P, ctr, cand, A);
    k_sort<<<B, 1024, 0, stream>>>(cand, ctr, top_idx, top_sc, A);
    k_nms<<<B, 256, 0, stream>>>(logits, rel, anch, top_idx, top_sc, out, A, B);
}